// Round 1
// baseline (474.816 us; speedup 1.0000x reference)
//
#include <hip/hip_runtime.h>
#include <math.h>

// CerberusSemanticIDBranch — fused prototype-softmax-affinity kernel for MI355X.
//
// out[r,g,:] = (e_g @ M'_g) / sum(e_g),  e_k = exp(l_k - max_g),
// l_k = (x_r . Pn_k) / ((||x_r||+1e-6) * tau),  Pn_k = P_k/(||P_k||+1e-6),
// M'_g = A_g @ P_g / (rowsum(A_g)+1e-6)   (rowsum(A) is constant per group).

constexpr int D    = 512;
constexpr int KTOT = 121;
constexpr int KPAD = 128;
constexpr float TAU = 0.07f;

constexpr int GB[5]  = {0, 2, 17, 57, 97};   // group base row in concat [121] layout
constexpr int GK[5]  = {2, 15, 40, 40, 24};  // prototypes per group
constexpr int GD2[5] = {1, 3, 5, 5, 4};      // second attribute cardinality
constexpr int GNA[5] = {1, 2, 2, 2, 2};      // number of attributes

__device__ __forceinline__ const float* pick(int k,
    const float* P0, const float* P1, const float* P2, const float* P3, const float* P4,
    int* kl) {
  if (k < 2)  { *kl = k;      return P0; }
  if (k < 17) { *kl = k - 2;  return P1; }
  if (k < 57) { *kl = k - 17; return P2; }
  if (k < 97) { *kl = k - 57; return P3; }
  *kl = k - 97; return P4;
}

__device__ __forceinline__ int pick_g(int k) {
  if (k < 2)  return 0;
  if (k < 17) return 1;
  if (k < 57) return 2;
  if (k < 97) return 3;
  return 4;
}

// ---- prep 1: inverse norms of the 121 prototype rows --------------------
__global__ void prep_norms(const float* __restrict__ P0, const float* __restrict__ P1,
                           const float* __restrict__ P2, const float* __restrict__ P3,
                           const float* __restrict__ P4, float* __restrict__ invn) {
  int k = blockIdx.x;  // 0..120
  int kl; const float* P = pick(k, P0, P1, P2, P3, P4, &kl);
  const float* row = P + (size_t)kl * D;
  float s = 0.f;
  for (int d = threadIdx.x; d < D; d += 64) { float v = row[d]; s += v * v; }
  #pragma unroll
  for (int m = 1; m < 64; m <<= 1) s += __shfl_xor(s, m);
  if (threadIdx.x == 0) invn[k] = 1.f / (sqrtf(s) + 1e-6f);
}

// ---- prep 2: PnT[d][kpad] = normalized prototypes, transposed -----------
__global__ void prep_pnt(const float* __restrict__ P0, const float* __restrict__ P1,
                         const float* __restrict__ P2, const float* __restrict__ P3,
                         const float* __restrict__ P4, const float* __restrict__ invn,
                         float* __restrict__ pnt) {
  int idx = blockIdx.x * 256 + threadIdx.x;  // 512 * 128 = 65536
  int d = idx >> 7, k = idx & (KPAD - 1);
  float v = 0.f;
  if (k < KTOT) {
    int kl; const float* P = pick(k, P0, P1, P2, P3, P4, &kl);
    v = P[(size_t)kl * D + d] * invn[k];
  }
  pnt[idx] = v;
}

// ---- prep 3: M'[k][d] = (A @ P)/(rowsum(A)+1e-6), concat over groups ----
__global__ void prep_m(const float* __restrict__ P0, const float* __restrict__ P1,
                       const float* __restrict__ P2, const float* __restrict__ P3,
                       const float* __restrict__ P4, float* __restrict__ mp) {
  int idx = blockIdx.x * 256 + threadIdx.x;  // 121*512 = 61952
  if (idx >= KTOT * D) return;
  int k = idx >> 9, d = idx & (D - 1);
  int kl; const float* P = pick(k, P0, P1, P2, P3, P4, &kl);
  int g = pick_g(k);
  int d2 = GD2[g], na = GNA[g], K = GK[g];
  int a1 = kl / d2, a2 = kl % d2;
  float s = 0.f, m = 0.f;
  for (int j = 0; j < K; j++) {
    float aff;
    if (na == 1) {
      aff = (j == kl) ? 1.f : 0.f;
    } else {
      int b1 = j / d2, b2 = j % d2;
      aff = 0.5f * (float)((a1 == b1) + (a2 == b2));
    }
    s += aff;
    m += aff * P[(size_t)j * D + d];
  }
  mp[idx] = m / (s + 1e-6f);
}

// ---- main fused kernel --------------------------------------------------
// grid 512 blocks x 128 threads. Block owns 64 rows; wave w handles d-half
// [w*256, w*256+256) for both the dot phase and the output phase. Partial
// dots are exchanged through LDS. lane <-> row so PnT/M' addresses are
// wave-uniform (scalar-load friendly; amortized across 64 rows).
__global__ __launch_bounds__(128) void fused_main(
    const float* __restrict__ x, const float* __restrict__ pnt,
    const float* __restrict__ mp, float* __restrict__ out) {
  __shared__ __align__(16) float red[2][64][124];
  const int tid  = threadIdx.x;
  const int lane = tid & 63;
  const int w    = __builtin_amdgcn_readfirstlane(tid >> 6);
  const int r    = blockIdx.x * 64 + lane;

  float acc[124];
  #pragma unroll
  for (int i = 0; i < 124; i++) acc[i] = 0.f;

  // ---- phase 1: partial dots over this wave's d-half ----
  const float* xrow = x + (size_t)r * D + w * 256;
  float xsq = 0.f;
  float4 xv = *(const float4*)xrow;
  #pragma unroll 1
  for (int d0 = 0; d0 < 256; d0 += 4) {
    float4 xnext = xv;
    if (d0 + 4 < 256) xnext = *(const float4*)(xrow + d0 + 4);  // prefetch
    const float* pr = pnt + (size_t)(w * 256 + d0) * KPAD;
    xsq += xv.x * xv.x + xv.y * xv.y + xv.z * xv.z + xv.w * xv.w;
    #pragma unroll
    for (int k = 0; k < KTOT; k++) acc[k] += xv.x * pr[k];
    #pragma unroll
    for (int k = 0; k < KTOT; k++) acc[k] += xv.y * pr[KPAD + k];
    #pragma unroll
    for (int k = 0; k < KTOT; k++) acc[k] += xv.z * pr[2 * KPAD + k];
    #pragma unroll
    for (int k = 0; k < KTOT; k++) acc[k] += xv.w * pr[3 * KPAD + k];
    xv = xnext;
  }
  acc[121] = xsq;  // ride the ||x||^2 partial through the same exchange
  acc[122] = 0.f; acc[123] = 0.f;

  // ---- cross-wave reduce via LDS ----
  #pragma unroll
  for (int j = 0; j < 31; j++) {
    ((float4*)&red[w][lane][0])[j] =
        make_float4(acc[4*j], acc[4*j+1], acc[4*j+2], acc[4*j+3]);
  }
  __syncthreads();
  #pragma unroll
  for (int j = 0; j < 31; j++) {
    float4 o = ((const float4*)&red[w ^ 1][lane][0])[j];
    acc[4*j] += o.x; acc[4*j+1] += o.y; acc[4*j+2] += o.z; acc[4*j+3] += o.w;
  }

  // ---- softmax per group; acc[k] becomes e_k / sum(e) ----
  const float scale = 1.f / (sqrtf(acc[121]) + 1e-6f) / TAU;
  #pragma unroll
  for (int g = 0; g < 5; g++) {
    float mx = -1e30f;
    #pragma unroll
    for (int kk = 0; kk < GK[g]; kk++) {
      int k = GB[g] + kk;
      acc[k] *= scale;
      mx = fmaxf(mx, acc[k]);
    }
    float E = 0.f;
    #pragma unroll
    for (int kk = 0; kk < GK[g]; kk++) {
      int k = GB[g] + kk;
      float e = __expf(acc[k] - mx);
      acc[k] = e;
      E += e;
    }
    float invE = 1.f / E;
    #pragma unroll
    for (int kk = 0; kk < GK[g]; kk++) acc[GB[g] + kk] *= invE;
  }

  // ---- phase 2: out[r,g,d] = sum_k c_k * M'[k][d] over this d-half ----
  float* orow = out + (size_t)r * (5 * D) + w * 256;
  #pragma unroll
  for (int g = 0; g < 5; g++) {
    #pragma unroll 1
    for (int dblk = 0; dblk < 256; dblk += 16) {
      float a[16];
      #pragma unroll
      for (int j = 0; j < 16; j++) a[j] = 0.f;
      #pragma unroll
      for (int kk = 0; kk < GK[g]; kk++) {
        const float c = acc[GB[g] + kk];
        const float* mrow = mp + (size_t)(GB[g] + kk) * D + w * 256 + dblk;
        #pragma unroll
        for (int j = 0; j < 16; j++) a[j] += c * mrow[j];
      }
      #pragma unroll
      for (int j4 = 0; j4 < 4; j4++)
        *(float4*)(orow + (size_t)g * D + dblk + 4 * j4) =
            make_float4(a[4*j4], a[4*j4+1], a[4*j4+2], a[4*j4+3]);
    }
  }
}

extern "C" void kernel_launch(void* const* d_in, const int* in_sizes, int n_in,
                              void* d_out, int out_size, void* d_ws, size_t ws_size,
                              hipStream_t stream) {
  const float* x  = (const float*)d_in[0];
  const float* P0 = (const float*)d_in[1];  // gender [2,512]
  const float* P1 = (const float*)d_in[2];  // hair   [15,512]
  const float* P2 = (const float*)d_in[3];  // top    [40,512]
  const float* P3 = (const float*)d_in[4];  // pants  [40,512]
  const float* P4 = (const float*)d_in[5];  // shoes  [24,512]
  float* out = (float*)d_out;

  float* ws   = (float*)d_ws;
  float* pnt  = ws;                         // 512*128 = 65536 floats
  float* mp   = ws + 65536;                 // 121*512 = 61952 floats
  float* invn = ws + 65536 + 61952;         // 121 floats

  prep_norms<<<dim3(121), dim3(64), 0, stream>>>(P0, P1, P2, P3, P4, invn);
  prep_pnt<<<dim3(256), dim3(256), 0, stream>>>(P0, P1, P2, P3, P4, invn, pnt);
  prep_m<<<dim3(242), dim3(256), 0, stream>>>(P0, P1, P2, P3, P4, mp);
  fused_main<<<dim3(512), dim3(128), 0, stream>>>(x, pnt, mp, out);
}

// Round 2
// 310.768 us; speedup vs baseline: 1.5279x; 1.5279x over previous
//
#include <hip/hip_runtime.h>
#include <math.h>

// CerberusSemanticIDBranch — fused prototype-softmax-affinity kernel for MI355X.
//
// out[r,g,:] = (e_g @ M'_g) / sum(e_g),  e_k = exp(l_k - max_g),
// l_k = (x_r . Pn_k) / ((||x_r||+1e-6) * tau),  Pn_k = P_k/(||P_k||+1e-6),
// M'_g = A_g @ P_g / (rowsum(A_g)+1e-6)   (rowsum(A) is constant per group).
//
// Main kernel: 512 blocks x 512 threads (8 waves). Block owns 64 rows
// (lane = row -> all Pn/M' accesses wave-uniform => scalar loads, amortized
// across 64 rows). Wave w owns d-slice [64w, 64w+64). Cross-wave dot
// reduction via ds_add_f32 into a single 32 KB LDS buffer (vs 62 KB ping-pong
// before): LDS no longer caps occupancy -> 16 waves/CU instead of 4.

constexpr int D    = 512;
constexpr int KTOT = 121;
constexpr int KPAD = 128;
constexpr float TAU = 0.07f;

constexpr int GB[5]  = {0, 2, 17, 57, 97};   // group base row in concat [121] layout
constexpr int GK[5]  = {2, 15, 40, 40, 24};  // prototypes per group
constexpr int GD2[5] = {1, 3, 5, 5, 4};      // second attribute cardinality
constexpr int GNA[5] = {1, 2, 2, 2, 2};      // number of attributes

__device__ __forceinline__ const float* pick(int k,
    const float* P0, const float* P1, const float* P2, const float* P3, const float* P4,
    int* kl) {
  if (k < 2)  { *kl = k;      return P0; }
  if (k < 17) { *kl = k - 2;  return P1; }
  if (k < 57) { *kl = k - 17; return P2; }
  if (k < 97) { *kl = k - 57; return P3; }
  *kl = k - 97; return P4;
}

__device__ __forceinline__ int pick_g(int k) {
  if (k < 2)  return 0;
  if (k < 17) return 1;
  if (k < 57) return 2;
  if (k < 97) return 3;
  return 4;
}

// ---- prep 1: inverse norms of the 121 prototype rows --------------------
__global__ void prep_norms(const float* __restrict__ P0, const float* __restrict__ P1,
                           const float* __restrict__ P2, const float* __restrict__ P3,
                           const float* __restrict__ P4, float* __restrict__ invn) {
  int k = blockIdx.x;  // 0..120
  int kl; const float* P = pick(k, P0, P1, P2, P3, P4, &kl);
  const float* row = P + (size_t)kl * D;
  float s = 0.f;
  for (int d = threadIdx.x; d < D; d += 64) { float v = row[d]; s += v * v; }
  #pragma unroll
  for (int m = 1; m < 64; m <<= 1) s += __shfl_xor(s, m);
  if (threadIdx.x == 0) invn[k] = 1.f / (sqrtf(s) + 1e-6f);
}

// ---- prep 2: PnT[d][kpad] = normalized prototypes, transposed -----------
__global__ void prep_pnt(const float* __restrict__ P0, const float* __restrict__ P1,
                         const float* __restrict__ P2, const float* __restrict__ P3,
                         const float* __restrict__ P4, const float* __restrict__ invn,
                         float* __restrict__ pnt) {
  int idx = blockIdx.x * 256 + threadIdx.x;  // 512 * 128 = 65536
  int d = idx >> 7, k = idx & (KPAD - 1);
  float v = 0.f;
  if (k < KTOT) {
    int kl; const float* P = pick(k, P0, P1, P2, P3, P4, &kl);
    v = P[(size_t)kl * D + d] * invn[k];
  }
  pnt[idx] = v;
}

// ---- prep 3: M'[k][d] = (A @ P)/(rowsum(A)+1e-6), concat over groups ----
__global__ void prep_m(const float* __restrict__ P0, const float* __restrict__ P1,
                       const float* __restrict__ P2, const float* __restrict__ P3,
                       const float* __restrict__ P4, float* __restrict__ mp) {
  int idx = blockIdx.x * 256 + threadIdx.x;  // 121*512 = 61952
  if (idx >= KTOT * D) return;
  int k = idx >> 9, d = idx & (D - 1);
  int kl; const float* P = pick(k, P0, P1, P2, P3, P4, &kl);
  int g = pick_g(k);
  int d2 = GD2[g], na = GNA[g], K = GK[g];
  int a1 = kl / d2, a2 = kl % d2;
  float s = 0.f, m = 0.f;
  for (int j = 0; j < K; j++) {
    float aff;
    if (na == 1) {
      aff = (j == kl) ? 1.f : 0.f;
    } else {
      int b1 = j / d2, b2 = j % d2;
      aff = 0.5f * (float)((a1 == b1) + (a2 == b2));
    }
    s += aff;
    m += aff * P[(size_t)j * D + d];
  }
  mp[idx] = m / (s + 1e-6f);
}

// ---- main fused kernel --------------------------------------------------
__global__ __launch_bounds__(512, 4) void fused_main(
    const float* __restrict__ x, const float* __restrict__ pnt,
    const float* __restrict__ mp, float* __restrict__ out) {
  // lred[k][row]: k-major so that for fixed k, 64 lanes hit 64 consecutive
  // dwords (2 lanes/bank = conflict-free). Slot 121 carries ||x||^2.
  __shared__ float lred[KPAD][64];
  const int tid  = threadIdx.x;
  const int lane = tid & 63;
  const int w    = __builtin_amdgcn_readfirstlane(tid >> 6);
  const int r    = blockIdx.x * 64 + lane;

  // zero the reduction buffer
  {
    float4* p4 = (float4*)&lred[0][0];
    #pragma unroll
    for (int i = 0; i < 4; i++) p4[tid + 512 * i] = make_float4(0.f, 0.f, 0.f, 0.f);
  }
  __syncthreads();

  const int dbase = w * 64;                       // this wave's d-slice
  const float* xrow = x + (size_t)r * D + dbase;  // lane's row, wave's slice

  // ---- phase 1, pass A: k in [0,64), plus ||x||^2 partial ----
  {
    float acc[64];
    #pragma unroll
    for (int i = 0; i < 64; i++) acc[i] = 0.f;
    float xsq = 0.f;
    float4 xv = *(const float4*)xrow;
    #pragma unroll 1
    for (int d0 = 0; d0 < 64; d0 += 4) {
      float4 xn = xv;
      if (d0 + 4 < 64) xn = *(const float4*)(xrow + d0 + 4);  // prefetch
      const float* pr = pnt + (size_t)(dbase + d0) * KPAD;    // wave-uniform
      xsq += xv.x * xv.x + xv.y * xv.y + xv.z * xv.z + xv.w * xv.w;
      #pragma unroll
      for (int k = 0; k < 64; k++) acc[k] += xv.x * pr[k];
      #pragma unroll
      for (int k = 0; k < 64; k++) acc[k] += xv.y * pr[KPAD + k];
      #pragma unroll
      for (int k = 0; k < 64; k++) acc[k] += xv.z * pr[2 * KPAD + k];
      #pragma unroll
      for (int k = 0; k < 64; k++) acc[k] += xv.w * pr[3 * KPAD + k];
      xv = xn;
    }
    #pragma unroll
    for (int k = 0; k < 64; k++) atomicAdd(&lred[k][lane], acc[k]);
    atomicAdd(&lred[121][lane], xsq);
  }

  // ---- phase 1, pass B: k in [64,121) ----
  {
    float acc[57];
    #pragma unroll
    for (int i = 0; i < 57; i++) acc[i] = 0.f;
    float4 xv = *(const float4*)xrow;
    #pragma unroll 1
    for (int d0 = 0; d0 < 64; d0 += 4) {
      float4 xn = xv;
      if (d0 + 4 < 64) xn = *(const float4*)(xrow + d0 + 4);
      const float* pr = pnt + (size_t)(dbase + d0) * KPAD + 64;
      #pragma unroll
      for (int k = 0; k < 57; k++) acc[k] += xv.x * pr[k];
      #pragma unroll
      for (int k = 0; k < 57; k++) acc[k] += xv.y * pr[KPAD + k];
      #pragma unroll
      for (int k = 0; k < 57; k++) acc[k] += xv.z * pr[2 * KPAD + k];
      #pragma unroll
      for (int k = 0; k < 57; k++) acc[k] += xv.w * pr[3 * KPAD + k];
      xv = xn;
    }
    #pragma unroll
    for (int k = 0; k < 57; k++) atomicAdd(&lred[64 + k][lane], acc[k]);
  }
  __syncthreads();

  // ---- softmax per group (wave 0 only; lane = row), in-place in LDS ----
  if (w == 0) {
    const float xs = lred[121][lane];
    const float scale = 1.f / ((sqrtf(xs) + 1e-6f) * TAU);
    #pragma unroll
    for (int g = 0; g < 5; g++) {
      float e[40];
      float mx = -1e30f;
      #pragma unroll
      for (int kk = 0; kk < GK[g]; kk++) {
        float v = lred[GB[g] + kk][lane] * scale;
        e[kk] = v;
        mx = fmaxf(mx, v);
      }
      float E = 0.f;
      #pragma unroll
      for (int kk = 0; kk < GK[g]; kk++) {
        float t = __expf(e[kk] - mx);
        e[kk] = t;
        E += t;
      }
      const float inv = 1.f / E;
      #pragma unroll
      for (int kk = 0; kk < GK[g]; kk++) lred[GB[g] + kk][lane] = e[kk] * inv;
    }
  }
  __syncthreads();

  // ---- phase 2: out[r,g,dslice] = sum_k c_k * M'[k][dslice] ----
  float* orow = out + (size_t)r * (5 * D) + dbase;
  #pragma unroll 1
  for (int g = 0; g < 5; g++) {
    float a[64];
    #pragma unroll
    for (int j = 0; j < 64; j++) a[j] = 0.f;
    #pragma unroll 1
    for (int kk = 0; kk < GK[g]; kk++) {
      const float c = lred[GB[g] + kk][lane];
      const float* mr = mp + (size_t)(GB[g] + kk) * D + dbase;  // wave-uniform
      #pragma unroll
      for (int j = 0; j < 64; j++) a[j] += c * mr[j];
    }
    #pragma unroll
    for (int j4 = 0; j4 < 16; j4++)
      *(float4*)(orow + (size_t)g * D + 4 * j4) =
          make_float4(a[4*j4], a[4*j4+1], a[4*j4+2], a[4*j4+3]);
  }
}

extern "C" void kernel_launch(void* const* d_in, const int* in_sizes, int n_in,
                              void* d_out, int out_size, void* d_ws, size_t ws_size,
                              hipStream_t stream) {
  const float* x  = (const float*)d_in[0];
  const float* P0 = (const float*)d_in[1];  // gender [2,512]
  const float* P1 = (const float*)d_in[2];  // hair   [15,512]
  const float* P2 = (const float*)d_in[3];  // top    [40,512]
  const float* P3 = (const float*)d_in[4];  // pants  [40,512]
  const float* P4 = (const float*)d_in[5];  // shoes  [24,512]
  float* out = (float*)d_out;

  float* ws   = (float*)d_ws;
  float* pnt  = ws;                         // 512*128 = 65536 floats
  float* mp   = ws + 65536;                 // 121*512 = 61952 floats
  float* invn = ws + 65536 + 61952;         // 121 floats

  prep_norms<<<dim3(121), dim3(64), 0, stream>>>(P0, P1, P2, P3, P4, invn);
  prep_pnt<<<dim3(256), dim3(256), 0, stream>>>(P0, P1, P2, P3, P4, invn, pnt);
  prep_m<<<dim3(242), dim3(256), 0, stream>>>(P0, P1, P2, P3, P4, mp);
  fused_main<<<dim3(512), dim3(512), 0, stream>>>(x, pnt, mp, out);
}

// Round 3
// 247.308 us; speedup vs baseline: 1.9199x; 1.2566x over previous
//
#include <hip/hip_runtime.h>
#include <math.h>

// CerberusSemanticIDBranch — fused prototype-softmax-affinity kernel for MI355X.
//
// out[r,g,:] = (e_g @ M'_g) / sum(e_g),  e_k = exp(l_k - max_g),
// l_k = (x_r . Pn_k) / ((||x_r||+1e-6) * tau),  Pn_k = P_k/(||P_k||+1e-6),
// M'_g = A_g @ P_g / (rowsum(A_g)+1e-6)   (rowsum(A) is constant per group).
//
// fused_main: 512 blocks x 512 threads (8 waves), block owns 64 rows
// (lane = row). Phase 1: wave w owns a k-chunk (waves 0-6: 15 protos + ||x||^2,
// wave 7: 16 protos -> 16 FMA/d everywhere), accumulates over ALL of D in
// acc[<=16] registers (no spill, no LDS atomics); x is staged in LDS in
// 64-column tiles (coalesced global reads, conflict-free pad-65 layout);
// prototypes stream as wave-uniform s_load from a chunk-major layout.
// Softmax: waves 0-4, one group each, 3-pass in LDS. Phase 2: 80 (g,32-col)
// tiles round-robin across waves, a[32] registers, wave-uniform mp rows.

constexpr int D    = 512;
constexpr int KTOT = 121;
constexpr int CK   = 16;    // k-slots per chunk (wave)
constexpr int DSTAGE = 64;  // x columns staged per iteration
constexpr float TAU = 0.07f;

constexpr int GB[5]  = {0, 2, 17, 57, 97};   // group base row in concat [121] layout
constexpr int GK[5]  = {2, 15, 40, 40, 24};  // prototypes per group
constexpr int GD2[5] = {1, 3, 5, 5, 4};      // second attribute cardinality
constexpr int GNA[5] = {1, 2, 2, 2, 2};      // number of attributes

__device__ __forceinline__ const float* pick(int k,
    const float* P0, const float* P1, const float* P2, const float* P3, const float* P4,
    int* kl) {
  if (k < 2)  { *kl = k;      return P0; }
  if (k < 17) { *kl = k - 2;  return P1; }
  if (k < 57) { *kl = k - 17; return P2; }
  if (k < 97) { *kl = k - 57; return P3; }
  *kl = k - 97; return P4;
}

__device__ __forceinline__ int pick_g(int k) {
  if (k < 2)  return 0;
  if (k < 17) return 1;
  if (k < 57) return 2;
  if (k < 97) return 3;
  return 4;
}

// ---- prep 1: inverse norms of the 121 prototype rows --------------------
__global__ void prep_norms(const float* __restrict__ P0, const float* __restrict__ P1,
                           const float* __restrict__ P2, const float* __restrict__ P3,
                           const float* __restrict__ P4, float* __restrict__ invn) {
  int k = blockIdx.x;  // 0..120
  int kl; const float* P = pick(k, P0, P1, P2, P3, P4, &kl);
  const float* row = P + (size_t)kl * D;
  float s = 0.f;
  for (int d = threadIdx.x; d < D; d += 64) { float v = row[d]; s += v * v; }
  #pragma unroll
  for (int m = 1; m < 64; m <<= 1) s += __shfl_xor(s, m);
  if (threadIdx.x == 0) invn[k] = 1.f / (sqrtf(s) + 1e-6f);
}

// ---- prep 2: pnt2[chunk][d][16] = normalized prototypes, chunk-major ----
// chunk c<7 slot j<15 -> k = 15c+j (slot 15 = zero pad); chunk 7 -> k = 105+j.
__global__ void prep_pnt2(const float* __restrict__ P0, const float* __restrict__ P1,
                          const float* __restrict__ P2, const float* __restrict__ P3,
                          const float* __restrict__ P4, const float* __restrict__ invn,
                          float* __restrict__ pnt2) {
  int idx = blockIdx.x * 256 + threadIdx.x;  // 8*512*16 = 65536
  int c = idx >> 13, rem = idx & 8191;
  int d = rem >> 4, j = rem & 15;
  int k = (c < 7) ? ((j < 15) ? 15 * c + j : -1) : 105 + j;
  float v = 0.f;
  if (k >= 0) {
    int kl; const float* P = pick(k, P0, P1, P2, P3, P4, &kl);
    v = P[(size_t)kl * D + d] * invn[k];
  }
  pnt2[idx] = v;
}

// ---- prep 3: M'[k][d] = (A @ P)/(rowsum(A)+1e-6), concat over groups ----
__global__ void prep_m(const float* __restrict__ P0, const float* __restrict__ P1,
                       const float* __restrict__ P2, const float* __restrict__ P3,
                       const float* __restrict__ P4, float* __restrict__ mp) {
  int idx = blockIdx.x * 256 + threadIdx.x;  // 121*512 = 61952
  if (idx >= KTOT * D) return;
  int k = idx >> 9, d = idx & (D - 1);
  int kl; const float* P = pick(k, P0, P1, P2, P3, P4, &kl);
  int g = pick_g(k);
  int d2 = GD2[g], na = GNA[g], K = GK[g];
  int a1 = kl / d2, a2 = kl % d2;
  float s = 0.f, m = 0.f;
  for (int j = 0; j < K; j++) {
    float aff;
    if (na == 1) {
      aff = (j == kl) ? 1.f : 0.f;
    } else {
      int b1 = j / d2, b2 = j % d2;
      aff = 0.5f * (float)((a1 == b1) + (a2 == b2));
    }
    s += aff;
    m += aff * P[(size_t)j * D + d];
  }
  mp[idx] = m / (s + 1e-6f);
}

// ---- main fused kernel --------------------------------------------------
__global__ __launch_bounds__(512, 4) void fused_main(
    const float* __restrict__ x, const float* __restrict__ pnt2,
    const float* __restrict__ mp, float* __restrict__ out) {
  __shared__ float lred[KTOT + 1][64];   // [122][64]: dots then c; slot 121 = ||x||^2
  __shared__ float xs[DSTAGE][65];       // staged x columns, pad-65 (conflict-free)

  const int tid  = threadIdx.x;
  const int lane = tid & 63;
  const int w    = __builtin_amdgcn_readfirstlane(tid >> 6);
  const int r0   = blockIdx.x * 64;
  const int r    = r0 + lane;

  float acc[CK];
  #pragma unroll
  for (int i = 0; i < CK; ++i) acc[i] = 0.f;
  float xsq = 0.f;

  // cooperative x-load mapping: 8 threads per row, 2 float4 each per stage
  const int lrow = tid >> 3;
  const int lc4  = (tid & 7) * 4;
  const float* xsrc  = x + (size_t)(r0 + lrow) * D + lc4;
  const float* pbase = pnt2 + (size_t)w * D * CK;

  for (int s = 0; s < D / DSTAGE; ++s) {
    float4 v0 = *(const float4*)(xsrc + s * DSTAGE);
    float4 v1 = *(const float4*)(xsrc + s * DSTAGE + 32);
    __syncthreads();  // previous stage's compute done before overwrite
    xs[lc4 + 0][lrow] = v0.x; xs[lc4 + 1][lrow] = v0.y;
    xs[lc4 + 2][lrow] = v0.z; xs[lc4 + 3][lrow] = v0.w;
    xs[lc4 + 32][lrow] = v1.x; xs[lc4 + 33][lrow] = v1.y;
    xs[lc4 + 34][lrow] = v1.z; xs[lc4 + 35][lrow] = v1.w;
    __syncthreads();
    const float* pr = pbase + (size_t)(s * DSTAGE) * CK;
    if (w < 7) {
      #pragma unroll 4
      for (int d = 0; d < DSTAGE; ++d) {
        float xv = xs[d][lane];
        #pragma unroll
        for (int j = 0; j < 15; ++j) acc[j] += xv * pr[d * CK + j];
        xsq += xv * xv;
      }
    } else {
      #pragma unroll 4
      for (int d = 0; d < DSTAGE; ++d) {
        float xv = xs[d][lane];
        #pragma unroll
        for (int j = 0; j < 16; ++j) acc[j] += xv * pr[d * CK + j];
      }
    }
  }

  // write final dots (plain ds_write, no atomics)
  if (w < 7) {
    #pragma unroll
    for (int j = 0; j < 15; ++j) lred[15 * w + j][lane] = acc[j];
    if (w == 0) lred[KTOT][lane] = xsq;
  } else {
    #pragma unroll
    for (int j = 0; j < 16; ++j) lred[105 + j][lane] = acc[j];
  }
  __syncthreads();

  // ---- softmax per group (wave g handles group g; lane = row), 3-pass ----
  if (w < 5) {
    const int g = w;
    const float scale = 1.f / ((sqrtf(lred[KTOT][lane]) + 1e-6f) * TAU);
    float mx = -1e30f;
    for (int kk = 0; kk < GK[g]; ++kk)
      mx = fmaxf(mx, lred[GB[g] + kk][lane]);
    float E = 0.f;
    for (int kk = 0; kk < GK[g]; ++kk) {
      float e = __expf((lred[GB[g] + kk][lane] - mx) * scale);
      lred[GB[g] + kk][lane] = e;
      E += e;
    }
    const float inv = 1.f / E;
    for (int kk = 0; kk < GK[g]; ++kk) lred[GB[g] + kk][lane] *= inv;
  }
  __syncthreads();

  // ---- phase 2: out[r, g*512 + d0..d0+31] over 80 tiles ----
  for (int t = w; t < 80; t += 8) {
    const int g  = t >> 4;
    const int d0 = (t & 15) * 32;
    float a[32];
    #pragma unroll
    for (int j = 0; j < 32; ++j) a[j] = 0.f;
    const int kb = GB[g], ke = GB[g] + GK[g];
    for (int k = kb; k < ke; ++k) {
      const float c = lred[k][lane];
      const float* mr = mp + (size_t)k * D + d0;  // wave-uniform
      #pragma unroll
      for (int j = 0; j < 32; ++j) a[j] += c * mr[j];
    }
    float* op = out + (size_t)r * (5 * D) + g * D + d0;
    #pragma unroll
    for (int j4 = 0; j4 < 8; ++j4)
      *(float4*)(op + 4 * j4) =
          make_float4(a[4*j4], a[4*j4+1], a[4*j4+2], a[4*j4+3]);
  }
}

extern "C" void kernel_launch(void* const* d_in, const int* in_sizes, int n_in,
                              void* d_out, int out_size, void* d_ws, size_t ws_size,
                              hipStream_t stream) {
  const float* x  = (const float*)d_in[0];
  const float* P0 = (const float*)d_in[1];  // gender [2,512]
  const float* P1 = (const float*)d_in[2];  // hair   [15,512]
  const float* P2 = (const float*)d_in[3];  // top    [40,512]
  const float* P3 = (const float*)d_in[4];  // pants  [40,512]
  const float* P4 = (const float*)d_in[5];  // shoes  [24,512]
  float* out = (float*)d_out;

  float* ws   = (float*)d_ws;
  float* pnt2 = ws;                         // 8*512*16 = 65536 floats
  float* mp   = ws + 65536;                 // 121*512  = 61952 floats
  float* invn = ws + 65536 + 61952;         // 121 floats

  prep_norms<<<dim3(121), dim3(64), 0, stream>>>(P0, P1, P2, P3, P4, invn);
  prep_pnt2<<<dim3(256), dim3(256), 0, stream>>>(P0, P1, P2, P3, P4, invn, pnt2);
  prep_m<<<dim3(242), dim3(256), 0, stream>>>(P0, P1, P2, P3, P4, mp);
  fused_main<<<dim3(512), dim3(512), 0, stream>>>(x, pnt2, mp, out);
}

// Round 4
// 195.169 us; speedup vs baseline: 2.4328x; 1.2671x over previous
//
#include <hip/hip_runtime.h>
#include <hip/hip_bf16.h>
#include <math.h>

// CerberusSemanticIDBranch — fused prototype-softmax-affinity kernel for MI355X.
//
// out[r,g,:] = (e_g @ M'_g) / sum(e_g),  e_k = exp(l_k - max_g),
// l_k = (x_r . Pn_k) / ((||x_r||+1e-6) * tau),  Pn_k = P_k/(||P_k||+1e-6),
// M'_g = A_g @ P_g / (rowsum(A_g)+1e-6)   (rowsum(A) is constant per group).
//
// Round 4: phase 1 (x @ Pn^T, 4.1 GFLOP = 60% of VALU work) moved to bf16
// MFMA (mfma_f32_16x16x32_bf16); ||x||^2 accumulated in fp32 from the same
// x loads; softmax + phase 2 (affinity-smoothed output, 330 MB stores) stay
// pure fp32 and reuse round-3's verified code. 512 blocks x 8 waves, block
// owns 64 rows; wave (w&3) = 16-row slab, (w>>2) = 64-col half.

constexpr int D    = 512;
constexpr int KTOT = 121;
constexpr float TAU = 0.07f;

constexpr int GB[5]  = {0, 2, 17, 57, 97};   // group base row in concat [121] layout
constexpr int GK[5]  = {2, 15, 40, 40, 24};  // prototypes per group
constexpr int GD2[5] = {1, 3, 5, 5, 4};      // second attribute cardinality
constexpr int GNA[5] = {1, 2, 2, 2, 2};      // number of attributes

using f32x4 = __attribute__((ext_vector_type(4))) float;
using s16x8 = __attribute__((ext_vector_type(8))) short;

__device__ __forceinline__ const float* pick(int k,
    const float* P0, const float* P1, const float* P2, const float* P3, const float* P4,
    int* kl) {
  if (k < 2)  { *kl = k;      return P0; }
  if (k < 17) { *kl = k - 2;  return P1; }
  if (k < 57) { *kl = k - 17; return P2; }
  if (k < 97) { *kl = k - 57; return P3; }
  *kl = k - 97; return P4;
}

__device__ __forceinline__ int pick_g(int k) {
  if (k < 2)  return 0;
  if (k < 17) return 1;
  if (k < 57) return 2;
  if (k < 97) return 3;
  return 4;
}

__device__ __forceinline__ short f2bf(float f) {
  __hip_bfloat16 h = __float2bfloat16(f);   // RTNE
  return *reinterpret_cast<short*>(&h);
}

// ---- prep 1: inverse norms of the 121 prototype rows --------------------
__global__ void prep_norms(const float* __restrict__ P0, const float* __restrict__ P1,
                           const float* __restrict__ P2, const float* __restrict__ P3,
                           const float* __restrict__ P4, float* __restrict__ invn) {
  int k = blockIdx.x;  // 0..120
  int kl; const float* P = pick(k, P0, P1, P2, P3, P4, &kl);
  const float* row = P + (size_t)kl * D;
  float s = 0.f;
  for (int d = threadIdx.x; d < D; d += 64) { float v = row[d]; s += v * v; }
  #pragma unroll
  for (int m = 1; m < 64; m <<= 1) s += __shfl_xor(s, m);
  if (threadIdx.x == 0) invn[k] = 1.f / (sqrtf(s) + 1e-6f);
}

// ---- prep 2: pnb[c][k] = bf16(Pn[c][k]), rows 121..127 zero -------------
__global__ void prep_pnb(const float* __restrict__ P0, const float* __restrict__ P1,
                         const float* __restrict__ P2, const float* __restrict__ P3,
                         const float* __restrict__ P4, const float* __restrict__ invn,
                         unsigned short* __restrict__ pnb) {
  int idx = blockIdx.x * 256 + threadIdx.x;  // 128*512 = 65536
  int c = idx >> 9, k = idx & (D - 1);
  float v = 0.f;
  if (c < KTOT) {
    int kl; const float* P = pick(c, P0, P1, P2, P3, P4, &kl);
    v = P[(size_t)kl * D + k] * invn[c];
  }
  pnb[idx] = (unsigned short)f2bf(v);
}

// ---- prep 3: M'[k][d] = (A @ P)/(rowsum(A)+1e-6), concat over groups ----
__global__ void prep_m(const float* __restrict__ P0, const float* __restrict__ P1,
                       const float* __restrict__ P2, const float* __restrict__ P3,
                       const float* __restrict__ P4, float* __restrict__ mp) {
  int idx = blockIdx.x * 256 + threadIdx.x;  // 121*512 = 61952
  if (idx >= KTOT * D) return;
  int k = idx >> 9, d = idx & (D - 1);
  int kl; const float* P = pick(k, P0, P1, P2, P3, P4, &kl);
  int g = pick_g(k);
  int d2 = GD2[g], na = GNA[g], K = GK[g];
  int a1 = kl / d2, a2 = kl % d2;
  float s = 0.f, m = 0.f;
  for (int j = 0; j < K; j++) {
    float aff;
    if (na == 1) {
      aff = (j == kl) ? 1.f : 0.f;
    } else {
      int b1 = j / d2, b2 = j % d2;
      aff = 0.5f * (float)((a1 == b1) + (a2 == b2));
    }
    s += aff;
    m += aff * P[(size_t)j * D + d];
  }
  mp[idx] = m / (s + 1e-6f);
}

// ---- main fused kernel --------------------------------------------------
__global__ __launch_bounds__(512, 4) void fused_main(
    const float* __restrict__ x, const unsigned short* __restrict__ pnb,
    const float* __restrict__ mp, float* __restrict__ out) {
  __shared__ float lred[128][65];  // [k][row], pad-65 (conflict-free both ways)
  __shared__ float xsqs[64];       // ||x||^2 per block-row

  const int tid  = threadIdx.x;
  const int lane = tid & 63;
  const int w    = __builtin_amdgcn_readfirstlane(tid >> 6);
  const int r0   = blockIdx.x * 64;

  const int wr = (w & 3) << 4;   // wave's 16-row slab (block-local)
  const int ch = w >> 2;         // column half: cols [64*ch, 64*ch+64)

  // ---- phase 1: 16x64 logit tile via MFMA, K = 512 ----
  // A-frag: lane holds x[r0+wr+(lane&15)][kstep*32 + (lane>>4)*8 + 0..7]
  // B-frag: lane holds Pn[64*ch+16*t+(lane&15)][same k slice]
  const int ko   = (lane >> 4) << 3;
  const int arow = wr + (lane & 15);
  const float* xrow = x + (size_t)(r0 + arow) * D + ko;

  f32x4 acc[4];
  #pragma unroll
  for (int t = 0; t < 4; ++t) acc[t] = (f32x4){0.f, 0.f, 0.f, 0.f};
  float xsq = 0.f;

  #pragma unroll 4
  for (int s = 0; s < 16; ++s) {
    float4 a0 = *(const float4*)(xrow + s * 32);
    float4 a1 = *(const float4*)(xrow + s * 32 + 4);
    xsq += a0.x * a0.x + a0.y * a0.y + a0.z * a0.z + a0.w * a0.w
         + a1.x * a1.x + a1.y * a1.y + a1.z * a1.z + a1.w * a1.w;
    s16x8 af;
    af[0] = f2bf(a0.x); af[1] = f2bf(a0.y); af[2] = f2bf(a0.z); af[3] = f2bf(a0.w);
    af[4] = f2bf(a1.x); af[5] = f2bf(a1.y); af[6] = f2bf(a1.z); af[7] = f2bf(a1.w);
    #pragma unroll
    for (int t = 0; t < 4; ++t) {
      const int col = (ch << 6) + (t << 4) + (lane & 15);
      s16x8 bfv = *(const s16x8*)(pnb + (size_t)col * D + s * 32 + ko);
      acc[t] = __builtin_amdgcn_mfma_f32_16x16x32_bf16(af, bfv, acc[t], 0, 0, 0);
    }
  }

  // ||x||^2: lanes {l, l^16, l^32, l^48} share the same A-row
  xsq += __shfl_xor(xsq, 16);
  xsq += __shfl_xor(xsq, 32);
  if (w < 4 && lane < 16) xsqs[wr + lane] = xsq;

  // dump C-frags to lred: D-tile mapping col=lane&15, row=(lane>>4)*4+j
  {
    const int drow = wr + ((lane >> 4) << 2);
    #pragma unroll
    for (int t = 0; t < 4; ++t) {
      const int col = (ch << 6) + (t << 4) + (lane & 15);
      #pragma unroll
      for (int j = 0; j < 4; ++j) lred[col][drow + j] = acc[t][j];
    }
  }
  __syncthreads();

  // ---- softmax per group (wave g handles group g; lane = row), 3-pass ----
  if (w < 5) {
    const int g = w;
    const float scale = 1.f / ((sqrtf(xsqs[lane]) + 1e-6f) * TAU);
    float mx = -1e30f;
    for (int kk = 0; kk < GK[g]; ++kk)
      mx = fmaxf(mx, lred[GB[g] + kk][lane]);
    float E = 0.f;
    for (int kk = 0; kk < GK[g]; ++kk) {
      float e = __expf((lred[GB[g] + kk][lane] - mx) * scale);
      lred[GB[g] + kk][lane] = e;
      E += e;
    }
    const float inv = 1.f / E;
    for (int kk = 0; kk < GK[g]; ++kk) lred[GB[g] + kk][lane] *= inv;
  }
  __syncthreads();

  // ---- phase 2: out[r, g*512 + d0..d0+31] over 80 tiles ----
  const int r = r0 + lane;
  for (int t = w; t < 80; t += 8) {
    const int g  = t >> 4;
    const int d0 = (t & 15) * 32;
    float a[32];
    #pragma unroll
    for (int j = 0; j < 32; ++j) a[j] = 0.f;
    const int kb = GB[g], ke = GB[g] + GK[g];
    for (int k = kb; k < ke; ++k) {
      const float c = lred[k][lane];
      const float* mr = mp + (size_t)k * D + d0;  // wave-uniform
      #pragma unroll
      for (int j = 0; j < 32; ++j) a[j] += c * mr[j];
    }
    float* op = out + (size_t)r * (5 * D) + g * D + d0;
    #pragma unroll
    for (int j4 = 0; j4 < 8; ++j4)
      *(float4*)(op + 4 * j4) =
          make_float4(a[4*j4], a[4*j4+1], a[4*j4+2], a[4*j4+3]);
  }
}

extern "C" void kernel_launch(void* const* d_in, const int* in_sizes, int n_in,
                              void* d_out, int out_size, void* d_ws, size_t ws_size,
                              hipStream_t stream) {
  const float* x  = (const float*)d_in[0];
  const float* P0 = (const float*)d_in[1];  // gender [2,512]
  const float* P1 = (const float*)d_in[2];  // hair   [15,512]
  const float* P2 = (const float*)d_in[3];  // top    [40,512]
  const float* P3 = (const float*)d_in[4];  // pants  [40,512]
  const float* P4 = (const float*)d_in[5];  // shoes  [24,512]
  float* out = (float*)d_out;

  float* ws = (float*)d_ws;
  unsigned short* pnb = (unsigned short*)ws;   // 128*512 bf16 = 32768 floats-worth
  float* mp   = ws + 32768;                    // 121*512 = 61952 floats
  float* invn = ws + 32768 + 61952;            // 121 floats

  prep_norms<<<dim3(121), dim3(64), 0, stream>>>(P0, P1, P2, P3, P4, invn);
  prep_pnb<<<dim3(256), dim3(256), 0, stream>>>(P0, P1, P2, P3, P4, invn, pnb);
  prep_m<<<dim3(242), dim3(256), 0, stream>>>(P0, P1, P2, P3, P4, mp);
  fused_main<<<dim3(512), dim3(512), 0, stream>>>(x, pnb, mp, out);
}